// Round 5
// baseline (2878.070 us; speedup 1.0000x reference)
//
#include <hip/hip_runtime.h>
#include <hip/hip_bf16.h>

// Problem constants
#define BATCH   64
#define SEQ     512
#define IN0     512
#define HID     128
#define G3      384   // 3*HID
#define NLAY    5

// ---------------------------------------------------------------------------
// gemm_gx: gx[M=32768][384] = A[M][K] @ W[384][K]^T + bias[384]   (all fp32)
// Tile 64(M) x 64(N), block 256 threads, 4x4 microtile, K-step 32.
// ---------------------------------------------------------------------------
__global__ __launch_bounds__(256) void gemm_gx(const float* __restrict__ A,
                                               const float* __restrict__ W,
                                               const float* __restrict__ bias,
                                               float* __restrict__ gx,
                                               int K)
{
    __shared__ __align__(16) float As[32][68];
    __shared__ __align__(16) float Bs[32][68];

    const int row0 = blockIdx.x * 64;
    const int col0 = blockIdx.y * 64;
    const int tid  = threadIdx.x;
    const int tx   = tid & 15;
    const int ty   = tid >> 4;
    const int r    = tid >> 2;
    const int kc   = (tid & 3) * 8;

    float acc[4][4] = {};

    for (int k0 = 0; k0 < K; k0 += 32) {
        {
            const float* Ap = A + (size_t)(row0 + r) * K + k0 + kc;
            float4 a0 = *(const float4*)(Ap);
            float4 a1 = *(const float4*)(Ap + 4);
            As[kc + 0][r] = a0.x; As[kc + 1][r] = a0.y; As[kc + 2][r] = a0.z; As[kc + 3][r] = a0.w;
            As[kc + 4][r] = a1.x; As[kc + 5][r] = a1.y; As[kc + 6][r] = a1.z; As[kc + 7][r] = a1.w;
        }
        {
            const float* Wp = W + (size_t)(col0 + r) * K + k0 + kc;
            float4 b0 = *(const float4*)(Wp);
            float4 b1 = *(const float4*)(Wp + 4);
            Bs[kc + 0][r] = b0.x; Bs[kc + 1][r] = b0.y; Bs[kc + 2][r] = b0.z; Bs[kc + 3][r] = b0.w;
            Bs[kc + 4][r] = b1.x; Bs[kc + 5][r] = b1.y; Bs[kc + 6][r] = b1.z; Bs[kc + 7][r] = b1.w;
        }
        __syncthreads();

        #pragma unroll
        for (int kk = 0; kk < 32; kk++) {
            float4 a = *(const float4*)&As[kk][ty * 4];
            float4 b = *(const float4*)&Bs[kk][tx * 4];
            acc[0][0] = fmaf(a.x, b.x, acc[0][0]); acc[0][1] = fmaf(a.x, b.y, acc[0][1]);
            acc[0][2] = fmaf(a.x, b.z, acc[0][2]); acc[0][3] = fmaf(a.x, b.w, acc[0][3]);
            acc[1][0] = fmaf(a.y, b.x, acc[1][0]); acc[1][1] = fmaf(a.y, b.y, acc[1][1]);
            acc[1][2] = fmaf(a.y, b.z, acc[1][2]); acc[1][3] = fmaf(a.y, b.w, acc[1][3]);
            acc[2][0] = fmaf(a.z, b.x, acc[2][0]); acc[2][1] = fmaf(a.z, b.y, acc[2][1]);
            acc[2][2] = fmaf(a.z, b.z, acc[2][2]); acc[2][3] = fmaf(a.z, b.w, acc[2][3]);
            acc[3][0] = fmaf(a.w, b.x, acc[3][0]); acc[3][1] = fmaf(a.w, b.y, acc[3][1]);
            acc[3][2] = fmaf(a.w, b.z, acc[3][2]); acc[3][3] = fmaf(a.w, b.w, acc[3][3]);
        }
        __syncthreads();
    }

    float bb[4];
    #pragma unroll
    for (int j = 0; j < 4; j++) bb[j] = bias[col0 + tx * 4 + j];
    #pragma unroll
    for (int i = 0; i < 4; i++) {
        const int row = row0 + ty * 4 + i;
        float4 v;
        v.x = acc[i][0] + bb[0];
        v.y = acc[i][1] + bb[1];
        v.z = acc[i][2] + bb[2];
        v.w = acc[i][3] + bb[3];
        *(float4*)&gx[(size_t)row * G3 + col0 + tx * 4] = v;
    }
}

// ---------------------------------------------------------------------------
// gru_scan v5: v4 layout + LDS-flag barrier instead of __syncthreads.
// __syncthreads forces `s_waitcnt vmcnt(0)` (drains the in-flight gx prefetch
// loads every step = serial HBM latency). The flag barrier uses only DS ops
// (lgkmcnt), so global loads stay in flight across the step boundary.
//   wave w = tid>>6:  q = w & 3 (k-quarter), half = w >> 2
//   lane ℓ:  jr = half*64 + ℓ          (matvec rows {jr, jr+128, jr+256})
//            j0 = q*32 + (ℓ&31)        (finalize h index, redundant ×2)
// Weights: 96 VGPRs/thread. h broadcast via v_readlane (VALU pipe, no LDS).
// Partials: part[buf][row][gate*4+q] with 13-dword row stride (13 ⊥ 32 →
// conflict-free writes; finalize = 3× ds_read_b128).
// Race safety: DS ops complete in issue-order per wave, so a wave's arrive
// implies its partials are visible; monotonic counter + 2 buffers: a wave can
// only write buffer X after ALL waves arrived at step X-1, which implies all
// finished reading buffer X (reads precede the next arrive). 
// ---------------------------------------------------------------------------
__global__ __launch_bounds__(512, 2) void gru_scan(const float* __restrict__ gx,   // [BATCH][SEQ][384]
                                                   const float* __restrict__ w_hh, // [384][128] layer slice
                                                   const float* __restrict__ b_hh, // [384] layer slice
                                                   float* __restrict__ hseq)       // [BATCH][SEQ][128]
{
    const int b    = blockIdx.x;
    const int tid  = threadIdx.x;
    const int lane = tid & 63;
    const int wv   = tid >> 6;
    const int q    = wv & 3;        // wave-uniform k-quarter
    const int half = wv >> 2;
    const int jr   = half * 64 + lane;      // [0,128)
    const int j0   = q * 32 + (lane & 31);  // finalize h index
    const int ko   = q * 32;

    // partials: [buf][row][gate*4 + q] (+1 pad) — 2*128*13*4B = 13.3 KB
    __shared__ __align__(16) float part[2][128][13];
    __shared__ int barcnt;

    // ---- load this thread's 96 weights (3 rows x 32 k) into registers ----
    float wr[32], wz[32], wn[32];
    {
        const float4* Wr = (const float4*)(w_hh + (size_t)(jr      ) * HID + ko);
        const float4* Wz = (const float4*)(w_hh + (size_t)(jr + 128) * HID + ko);
        const float4* Wn = (const float4*)(w_hh + (size_t)(jr + 256) * HID + ko);
        #pragma unroll
        for (int p = 0; p < 8; p++) {
            float4 f;
            f = Wr[p]; wr[4*p] = f.x; wr[4*p+1] = f.y; wr[4*p+2] = f.z; wr[4*p+3] = f.w;
            f = Wz[p]; wz[4*p] = f.x; wz[4*p+1] = f.y; wz[4*p+2] = f.z; wz[4*p+3] = f.w;
            f = Wn[p]; wn[4*p] = f.x; wn[4*p+1] = f.y; wn[4*p+2] = f.z; wn[4*p+3] = f.w;
        }
    }
    const float bhr = b_hh[j0];
    const float bhz = b_hh[j0 + 128];
    const float bhn = b_hh[j0 + 256];

    const float* gxb  = gx   + (size_t)b * SEQ * G3;
    float*       hout = hseq + (size_t)b * SEQ * HID;
    const bool   st   = (half == 0) && (lane < 32);   // waves 0-3, lanes 0-31: each j once

    if (tid == 0) barcnt = 0;
    __syncthreads();   // once, at init (weight loads drain here — fine)

    // preload gx for t=0
    float xr = gxb[j0];
    float xz = gxb[j0 + 128];
    float xn = gxb[j0 + 256];
    const float* gp = gxb + G3;

    float vhs = 0.f;   // lane-held h[j0]
    int target = 0;

    volatile int* bc = &barcnt;

    for (int t = 0; t < SEQ; t++) {
        // prefetch gx for t+1 — stays in flight across the flag barrier
        float nxr = 0.f, nxz = 0.f, nxn = 0.f;
        if (t + 1 < SEQ) { nxr = gp[j0]; nxz = gp[j0 + 128]; nxn = gp[j0 + 256]; }
        gp += G3;

        // matvec quarter-dots: h[32q+k] broadcast from lane k via readlane (VALU)
        float ar = 0.f, az = 0.f, an = 0.f;
        #pragma unroll
        for (int k = 0; k < 32; k++) {
            const float hk = __int_as_float(__builtin_amdgcn_readlane(__float_as_int(vhs), k));
            ar = fmaf(wr[k], hk, ar);
            az = fmaf(wz[k], hk, az);
            an = fmaf(wn[k], hk, an);
        }
        const int buf = t & 1;
        float* pr = part[buf][jr];
        pr[q    ] = ar;
        pr[4 + q] = az;
        pr[8 + q] = an;

        // ---- LDS flag barrier (no vmcnt drain) ----
        __asm__ volatile("" ::: "memory");
        if (lane == 0) atomicAdd(&barcnt, 1);   // ds_add on LDS
        target += 8;
        while (*bc < target) { }                 // ds_read_b32 spin (wave-uniform)
        __asm__ volatile("" ::: "memory");

        // redundant finalize for j0: 3x b128 partial reads
        const float4 p0 = *(const float4*)&part[buf][j0][0];
        const float4 p1 = *(const float4*)&part[buf][j0][4];
        const float4 p2 = *(const float4*)&part[buf][j0][8];
        const float ghr = ((p0.x + p0.y) + (p0.z + p0.w)) + bhr;
        const float ghz = ((p1.x + p1.y) + (p1.z + p1.w)) + bhz;
        const float ghn = ((p2.x + p2.y) + (p2.z + p2.w)) + bhn;

        const float rg  = 1.f / (1.f + __expf(-(xr + ghr)));
        const float zg  = 1.f / (1.f + __expf(-(xz + ghz)));
        const float pre = xn + rg * ghn;
        const float e   = __expf(-2.f * fabsf(pre));
        const float th  = copysignf((1.f - e) / (1.f + e), pre);   // tanh(pre)
        const float hnew = fmaf(zg, vhs - th, th);                 // (1-z)*n + z*h
        vhs = hnew;
        if (st) hout[(size_t)t * HID + j0] = hnew;

        xr = nxr; xz = nxz; xn = nxn;
    }
}

// ---------------------------------------------------------------------------
// fc: out[b][o] = hseq[b][T-1][:] . fc_w[o][:] + fc_b[o]
// ---------------------------------------------------------------------------
__global__ __launch_bounds__(128) void fc_kernel(const float* __restrict__ hseq,
                                                 const float* __restrict__ fc_w,
                                                 const float* __restrict__ fc_b,
                                                 float* __restrict__ out)
{
    const int b = blockIdx.x;
    const int o = threadIdx.x;
    if (o < 96) {
        const float* h = hseq + (size_t)b * (SEQ * HID) + (size_t)(SEQ - 1) * HID;
        const float* wrow = fc_w + o * HID;
        float acc = fc_b[o];
        #pragma unroll 4
        for (int k = 0; k < HID; k++) acc = fmaf(h[k], wrow[k], acc);
        out[b * 96 + o] = acc;
    }
}

// ---------------------------------------------------------------------------
extern "C" void kernel_launch(void* const* d_in, const int* in_sizes, int n_in,
                              void* d_out, int out_size, void* d_ws, size_t ws_size,
                              hipStream_t stream)
{
    const float* x         = (const float*)d_in[0]; // [64][512][512]
    const float* w_ih0     = (const float*)d_in[1]; // [384][512]
    const float* w_ih_rest = (const float*)d_in[2]; // [4][384][128]
    const float* w_hh      = (const float*)d_in[3]; // [5][384][128]
    const float* b_ih      = (const float*)d_in[4]; // [5][384]
    const float* b_hh      = (const float*)d_in[5]; // [5][384]
    const float* fc_w      = (const float*)d_in[6]; // [96][128]
    const float* fc_b      = (const float*)d_in[7]; // [96]
    float* out = (float*)d_out;                     // [64][96]

    float* gxbuf = (float*)d_ws;                    // 32768*384 fp32 = 50.3 MB
    float* hseq  = gxbuf + (size_t)32768 * G3;      // 32768*128 fp32 = 16.8 MB

    const dim3 gemmGrid(512, 6);

    gemm_gx<<<gemmGrid, 256, 0, stream>>>(x, w_ih0, b_ih, gxbuf, IN0);
    gru_scan<<<BATCH, 512, 0, stream>>>(gxbuf, w_hh, b_hh, hseq);

    for (int l = 1; l < NLAY; l++) {
        gemm_gx<<<gemmGrid, 256, 0, stream>>>(hseq,
                                              w_ih_rest + (size_t)(l - 1) * G3 * HID,
                                              b_ih + (size_t)l * G3,
                                              gxbuf, HID);
        gru_scan<<<BATCH, 512, 0, stream>>>(gxbuf,
                                            w_hh + (size_t)l * G3 * HID,
                                            b_hh + (size_t)l * G3,
                                            hseq);
    }

    fc_kernel<<<BATCH, 128, 0, stream>>>(hseq, fc_w, fc_b, out);
}